// Round 3
// baseline (186.692 us; speedup 1.0000x reference)
//
#include <hip/hip_runtime.h>
#include <hip/hip_bf16.h>
#include <stdint.h>
#include <stddef.h>

// MDCT as folded GEMM, fold FUSED into GEMM B-staging:
//   out[512, 32784] = D[512,512] . V[512, 32784]
//   V[c][j] = j<256:  x[g+j] - x[g+511-j]
//             j>=256: x[g+j+256] + x[g+1279-j],   g = o*512 - 512 (per batch)
// Within a column each x sample is read exactly once across the two branches,
// so inline folding adds no redundant global traffic.
// Precision: single fp16 product (round 1/2 showed absmax=0.03125 is output
// bf16-ulp grain for both bf16x3 and fp16 -> fp16 is safely inside tolerance).

constexpr int N_ = 512;
constexpr int T_ = 2048;
constexpr int B_ = 16;
constexpr int LEN = N_ * T_;              // 1048576 = 2^20 per batch
constexpr int FRAMES = T_ + 1;            // 2049
constexpr int COLS = B_ * FRAMES;         // 32784
constexpr int NT_TILES = 257;
constexpr int KF = 512;
constexpr int BK = 64;

typedef __attribute__((ext_vector_type(8))) _Float16 f16x8;
typedef __attribute__((ext_vector_type(4))) _Float16 f16x4;
typedef __attribute__((ext_vector_type(4))) float f32x4;

#define GLD16(gptr, lptr)                                                     \
  __builtin_amdgcn_global_load_lds(                                           \
      (const __attribute__((address_space(1))) unsigned int*)(gptr),          \
      (__attribute__((address_space(3))) unsigned int*)(lptr), 16, 0, 0)

// ---------------- Kernel 1: gather filter -> fp16 D -------------------------
__global__ void prep_filter(const float* __restrict__ f,
                            _Float16* __restrict__ D) {
  int idx = (blockIdx.x * 256 + threadIdx.x) * 4;
  int k = idx >> 9;
  int j = idx & 511;
  int t = (j < 256) ? j : (j + 256);
  const float4 v = *(const float4*)&f[k * 1024 + t];
  f16x4 h = {(_Float16)v.x, (_Float16)v.y, (_Float16)v.z, (_Float16)v.w};
  *(f16x4*)&D[k * KF + j] = h;
}

// ---------------- Kernel 2: fused fold + GEMM -------------------------------
// 128x128 tile, BK=64, 4 waves (2x2 of 64x64), mfma_f32_16x16x32_f16.
// A (filter): GLD16 into XOR-swizzled LDS (verified round 2).
// B (signal): global float4 -> fold -> f16x8 -> ds_write_b128 into the SAME
// swizzled layout (slot = r*8 + (chunk ^ (r&7)); write side has no
// wave-uniform-base constraint so we can scatter directly).
__global__ __launch_bounds__(256, 3) void gemm_fused(
    const _Float16* __restrict__ D, const float* __restrict__ x,
    float* __restrict__ out) {
  __shared__ __align__(16) _Float16 As[128 * BK];
  __shared__ __align__(16) _Float16 Bs[128 * BK];

  const int m0 = blockIdx.x * 128;   // 4 m-tiles (fast axis; share x window)
  const int n0 = blockIdx.y * 128;   // 257 n-tiles
  const int tid = threadIdx.x;
  const int wid = tid >> 6;
  const int lane = tid & 63;
  const int quad = lane >> 4;
  const int l16 = lane & 15;
  const int mw = (wid >> 1) * 64;
  const int nw = (wid & 1) * 64;

  // Per-thread column precompute: this thread stages chunk (tid&7) of rows
  // r = u*32 + (tid>>3), u=0..3 — identical every k-iter.
  const int rbase = tid >> 3;          // 0..31
  const int cch = tid & 7;             // global k-chunk 0..7 within tile
  const int swz = cch ^ (rbase & 7);   // r&7 == rbase&7 (u*32 ≡ 0 mod 8)
  int gg[4], lo[4];
  bool ok[4];
#pragma unroll
  for (int u = 0; u < 4; ++u) {
    int r = u * 32 + rbase;
    int col = n0 + r;
    int b = (int)((unsigned)col / (unsigned)FRAMES);
    int o = col - b * FRAMES;
    gg[u] = b * LEN + o * N_ - N_;     // window start, absolute index (may be -512)
    lo[u] = b * LEN;                   // batch lower bound
    ok[u] = (col < COLS);
  }

  f32x4 acc[4][4];
#pragma unroll
  for (int i = 0; i < 4; ++i)
#pragma unroll
    for (int j = 0; j < 4; ++j) acc[i][j] = (f32x4){0.f, 0.f, 0.f, 0.f};

  const _Float16* Dm = D + (size_t)m0 * KF;

  for (int kt = 0; kt < KF / BK; ++kt) {  // 8 iterations
    const int kb = kt * BK;
    __syncthreads();  // previous tile fully consumed

    // ---- A staging: GLD16, swizzled (verified round 2) ----
#pragma unroll
    for (int u = 0; u < 4; ++u) {
      const int S = u * 256 + tid;
      const int rA = S >> 3;
      const int cA = (S & 7) ^ (rA & 7);
      GLD16(Dm + (size_t)rA * KF + kb + cA * 8, &As[S * 8]);
    }

    // ---- B staging: load x, fold, ds_write ----
    // j0..j0+7 handled by this thread (8 consecutive k). Branch is
    // block-uniform (kb < 256 for kt < 4). Both 8-float segments are
    // 8-aligned within the batch -> fully in or fully out (one predicate).
    const int j0 = kb + cch * 8;
    const bool mi = (kb < 256);
    const int fo = mi ? j0 : (j0 + 256);          // fwd segment start - gg
    const int ro = mi ? (504 - j0) : (1272 - j0); // rev segment start - gg
    const float sgn = mi ? -1.0f : 1.0f;
#pragma unroll
    for (int u = 0; u < 4; ++u) {
      float4 a0 = {0.f, 0.f, 0.f, 0.f}, a1 = {0.f, 0.f, 0.f, 0.f};
      float4 r0 = {0.f, 0.f, 0.f, 0.f}, r1 = {0.f, 0.f, 0.f, 0.f};
      if (ok[u]) {
        const int fb = gg[u] + fo;
        const int rb = gg[u] + ro;
        if ((unsigned)(fb - lo[u]) <= (unsigned)(LEN - 8)) {
          a0 = *(const float4*)(x + fb);
          a1 = *(const float4*)(x + fb + 4);
        }
        if ((unsigned)(rb - lo[u]) <= (unsigned)(LEN - 8)) {
          r0 = *(const float4*)(x + rb);
          r1 = *(const float4*)(x + rb + 4);
        }
      }
      // out[j0+i] = fwd[i] + sgn * x[.. - i] ; rev segment loaded ascending,
      // consumed reversed: j0+0 pairs with r1.w, j0+4 with r0.w, etc.
      f16x8 h;
      h[0] = (_Float16)__builtin_fmaf(sgn, r1.w, a0.x);
      h[1] = (_Float16)__builtin_fmaf(sgn, r1.z, a0.y);
      h[2] = (_Float16)__builtin_fmaf(sgn, r1.y, a0.z);
      h[3] = (_Float16)__builtin_fmaf(sgn, r1.x, a0.w);
      h[4] = (_Float16)__builtin_fmaf(sgn, r0.w, a1.x);
      h[5] = (_Float16)__builtin_fmaf(sgn, r0.z, a1.y);
      h[6] = (_Float16)__builtin_fmaf(sgn, r0.y, a1.z);
      h[7] = (_Float16)__builtin_fmaf(sgn, r0.x, a1.w);
      const int r = u * 32 + rbase;
      *(f16x8*)&Bs[(r * 8 + swz) * 8] = h;
    }
    __syncthreads();  // drains vmcnt (A GLD16) + lgkm (B writes): tiles ready

    // ---- fragment reads + MFMA (verified round 2) ----
#pragma unroll
    for (int ko = 0; ko < 2; ++ko) {
      f16x8 af[4], bf[4];
#pragma unroll
      for (int i = 0; i < 4; ++i) {
        int ra = mw + i * 16 + l16;
        int rb = nw + i * 16 + l16;
        int ca = ko * 4 + quad;
        af[i] = *(const f16x8*)&As[(ra * 8 + (ca ^ (ra & 7))) * 8];
        bf[i] = *(const f16x8*)&Bs[(rb * 8 + (ca ^ (rb & 7))) * 8];
      }
#pragma unroll
      for (int i = 0; i < 4; ++i)
#pragma unroll
        for (int j = 0; j < 4; ++j)
          acc[i][j] = __builtin_amdgcn_mfma_f32_16x16x32_f16(af[i], bf[j], acc[i][j], 0, 0, 0);
    }
  }

  // ---- epilogue (verified round 1/2): C/D layout col=lane&15, row=quad*4+reg
#pragma unroll
  for (int i = 0; i < 4; ++i) {
#pragma unroll
    for (int j = 0; j < 4; ++j) {
      int col = n0 + nw + j * 16 + l16;
      if (col < COLS) {
        int b = col / FRAMES;
        int o = col - b * FRAMES;
        int rowb = m0 + mw + i * 16 + quad * 4;
        float* op = out + (size_t)b * N_ * FRAMES + (size_t)rowb * FRAMES + o;
#pragma unroll
        for (int r = 0; r < 4; ++r) op[(size_t)r * FRAMES] = acc[i][j][r];
      }
    }
  }
}

// ---------------- Fallback: direct fp32 conv (if ws too small) --------------
__global__ void naive_conv(const float* __restrict__ x, const float* __restrict__ f,
                           float* __restrict__ out) {
  int col = blockIdx.x;
  int k = threadIdx.x;
  __shared__ float win[1024];
  int b = col / FRAMES;
  int o = col - b * FRAMES;
  const float* xb = x + (size_t)b * LEN;
  int g = o * N_ - N_;
  for (int t = threadIdx.x; t < 1024; t += 512) {
    int i = g + t;
    win[t] = (i >= 0 && i < LEN) ? xb[i] : 0.0f;
  }
  __syncthreads();
  float s = 0.0f;
  const float* fk = f + (size_t)k * 1024;
  for (int t = 0; t < 1024; ++t) s += win[t] * fk[t];
  out[(size_t)b * N_ * FRAMES + (size_t)k * FRAMES + o] = s;
}

extern "C" void kernel_launch(void* const* d_in, const int* in_sizes, int n_in,
                              void* d_out, int out_size, void* d_ws, size_t ws_size,
                              hipStream_t stream) {
  const float* x = (const float*)d_in[0];
  const float* f = (const float*)d_in[1];
  float* out = (float*)d_out;

  const size_t need = (size_t)512 * 512 * sizeof(_Float16);
  if (ws_size < need) {
    naive_conv<<<COLS, 512, 0, stream>>>(x, f, out);
    return;
  }

  _Float16* D = (_Float16*)d_ws;
  prep_filter<<<256, 256, 0, stream>>>(f, D);
  gemm_fused<<<dim3(4, NT_TILES), 256, 0, stream>>>(D, x, out);
}

// Round 5
// 160.174 us; speedup vs baseline: 1.1656x; 1.1656x over previous
//
#include <hip/hip_runtime.h>
#include <hip/hip_bf16.h>
#include <stdint.h>
#include <stddef.h>

// MDCT as folded GEMM, fold FUSED into GEMM B-staging:
//   out[512, 32784] = D[512,512] . V[512, 32784]
//   V[c][j] = j<256:  x[g+j] - x[g+511-j]
//             j>=256: x[g+j+256] + x[g+1279-j],   g = o*512 - 512 (per batch)
// Round-3 lesson (FETCH=263MB=4x67MB): the 4 m-blocks sharing an n-tile's
// x-window landed on 4 different XCDs, so per-XCD L2 never deduped the
// shared reads. Round 4/5: 1-D grid + swizzle so same-n blocks get ids
// congruent mod 8 -> same XCD, co-resident.
// Round-4 bug: grid 1032 missed m=1..3 of n-tile 256 (max id = 1048);
// grid must be 132*8 = 1056. Fixed here.
// Precision: single fp16 product; absmax 0.03125 vs threshold 0.1069.

constexpr int N_ = 512;
constexpr int T_ = 2048;
constexpr int B_ = 16;
constexpr int LEN = N_ * T_;              // 1048576 = 2^20 per batch
constexpr int FRAMES = T_ + 1;            // 2049
constexpr int COLS = B_ * FRAMES;         // 32784
constexpr int NT_TILES = 257;
constexpr int KF = 512;
constexpr int BK = 64;

typedef __attribute__((ext_vector_type(8))) _Float16 f16x8;
typedef __attribute__((ext_vector_type(4))) _Float16 f16x4;
typedef __attribute__((ext_vector_type(4))) float f32x4;

#define GLD16(gptr, lptr)                                                     \
  __builtin_amdgcn_global_load_lds(                                           \
      (const __attribute__((address_space(1))) unsigned int*)(gptr),          \
      (__attribute__((address_space(3))) unsigned int*)(lptr), 16, 0, 0)

// ---------------- Kernel 1: gather filter -> fp16 D -------------------------
__global__ void prep_filter(const float* __restrict__ f,
                            _Float16* __restrict__ D) {
  int idx = (blockIdx.x * 256 + threadIdx.x) * 4;
  int k = idx >> 9;
  int j = idx & 511;
  int t = (j < 256) ? j : (j + 256);
  const float4 v = *(const float4*)&f[k * 1024 + t];
  f16x4 h = {(_Float16)v.x, (_Float16)v.y, (_Float16)v.z, (_Float16)v.w};
  *(f16x4*)&D[k * KF + j] = h;
}

// ---------------- Kernel 2: fused fold + GEMM, XCD-swizzled grid ------------
// 128x128 tile, BK=64, 4 waves (2x2 of 64x64), mfma_f32_16x16x32_f16.
// Grid: 1056 blocks; id -> xcd=id&7, s=id>>3 (0..131), m-tile=s&3 (fastest,
// so the 4 sharers are consecutive within an XCD), n-tile=(s>>2)*8+xcd.
// Inverse: s=(nt>>3)*4+m, id=s*8+(nt&7); max id=1048 -> grid 1056.
__global__ __launch_bounds__(256, 3) void gemm_fused(
    const _Float16* __restrict__ D, const float* __restrict__ x,
    float* __restrict__ out) {
  __shared__ __align__(16) _Float16 As[128 * BK];
  __shared__ __align__(16) _Float16 Bs[128 * BK];

  const int id = blockIdx.x;
  const int xcd = id & 7;
  const int s = id >> 3;
  const int nt = (s >> 2) * 8 + xcd;
  if (nt >= NT_TILES) return;        // block-uniform exit (tail of swizzle map)
  const int m0 = (s & 3) * 128;
  const int n0 = nt * 128;

  const int tid = threadIdx.x;
  const int wid = tid >> 6;
  const int lane = tid & 63;
  const int quad = lane >> 4;
  const int l16 = lane & 15;
  const int mw = (wid >> 1) * 64;
  const int nw = (wid & 1) * 64;

  // Per-thread column precompute: this thread stages chunk (tid&7) of rows
  // r = u*32 + (tid>>3), u=0..3 — identical every k-iter.
  const int rbase = tid >> 3;          // 0..31
  const int cch = tid & 7;             // global k-chunk 0..7 within tile
  const int swz = cch ^ (rbase & 7);   // r&7 == rbase&7 (u*32 ≡ 0 mod 8)
  int gg[4], lo[4];
  bool ok[4];
#pragma unroll
  for (int u = 0; u < 4; ++u) {
    int r = u * 32 + rbase;
    int col = n0 + r;
    int b = (int)((unsigned)col / (unsigned)FRAMES);
    int o = col - b * FRAMES;
    gg[u] = b * LEN + o * N_ - N_;     // window start, absolute index (may be -512)
    lo[u] = b * LEN;                   // batch lower bound
    ok[u] = (col < COLS);
  }

  f32x4 acc[4][4];
#pragma unroll
  for (int i = 0; i < 4; ++i)
#pragma unroll
    for (int j = 0; j < 4; ++j) acc[i][j] = (f32x4){0.f, 0.f, 0.f, 0.f};

  const _Float16* Dm = D + (size_t)m0 * KF;

  for (int kt = 0; kt < KF / BK; ++kt) {  // 8 iterations
    const int kb = kt * BK;
    __syncthreads();  // previous tile fully consumed

    // ---- A staging: GLD16, swizzled (verified round 2) ----
#pragma unroll
    for (int u = 0; u < 4; ++u) {
      const int S = u * 256 + tid;
      const int rA = S >> 3;
      const int cA = (S & 7) ^ (rA & 7);
      GLD16(Dm + (size_t)rA * KF + kb + cA * 8, &As[S * 8]);
    }

    // ---- B staging: load x, fold, ds_write (verified round 3) ----
    const int j0 = kb + cch * 8;
    const bool mi = (kb < 256);
    const int fo = mi ? j0 : (j0 + 256);          // fwd segment start - gg
    const int ro = mi ? (504 - j0) : (1272 - j0); // rev segment start - gg
    const float sgn = mi ? -1.0f : 1.0f;
#pragma unroll
    for (int u = 0; u < 4; ++u) {
      float4 a0 = {0.f, 0.f, 0.f, 0.f}, a1 = {0.f, 0.f, 0.f, 0.f};
      float4 r0 = {0.f, 0.f, 0.f, 0.f}, r1 = {0.f, 0.f, 0.f, 0.f};
      if (ok[u]) {
        const int fb = gg[u] + fo;
        const int rb = gg[u] + ro;
        if ((unsigned)(fb - lo[u]) <= (unsigned)(LEN - 8)) {
          a0 = *(const float4*)(x + fb);
          a1 = *(const float4*)(x + fb + 4);
        }
        if ((unsigned)(rb - lo[u]) <= (unsigned)(LEN - 8)) {
          r0 = *(const float4*)(x + rb);
          r1 = *(const float4*)(x + rb + 4);
        }
      }
      f16x8 h;
      h[0] = (_Float16)__builtin_fmaf(sgn, r1.w, a0.x);
      h[1] = (_Float16)__builtin_fmaf(sgn, r1.z, a0.y);
      h[2] = (_Float16)__builtin_fmaf(sgn, r1.y, a0.z);
      h[3] = (_Float16)__builtin_fmaf(sgn, r1.x, a0.w);
      h[4] = (_Float16)__builtin_fmaf(sgn, r0.w, a1.x);
      h[5] = (_Float16)__builtin_fmaf(sgn, r0.z, a1.y);
      h[6] = (_Float16)__builtin_fmaf(sgn, r0.y, a1.z);
      h[7] = (_Float16)__builtin_fmaf(sgn, r0.x, a1.w);
      const int r = u * 32 + rbase;
      *(f16x8*)&Bs[(r * 8 + swz) * 8] = h;
    }
    __syncthreads();  // drains vmcnt (A GLD16) + lgkm (B writes): tiles ready

    // ---- fragment reads + MFMA (verified round 2) ----
#pragma unroll
    for (int ko = 0; ko < 2; ++ko) {
      f16x8 af[4], bf[4];
#pragma unroll
      for (int i = 0; i < 4; ++i) {
        int ra = mw + i * 16 + l16;
        int rb = nw + i * 16 + l16;
        int ca = ko * 4 + quad;
        af[i] = *(const f16x8*)&As[(ra * 8 + (ca ^ (ra & 7))) * 8];
        bf[i] = *(const f16x8*)&Bs[(rb * 8 + (ca ^ (rb & 7))) * 8];
      }
#pragma unroll
      for (int i = 0; i < 4; ++i)
#pragma unroll
        for (int j = 0; j < 4; ++j)
          acc[i][j] = __builtin_amdgcn_mfma_f32_16x16x32_f16(af[i], bf[j], acc[i][j], 0, 0, 0);
    }
  }

  // ---- epilogue (verified round 1/2): C/D layout col=lane&15, row=quad*4+reg
#pragma unroll
  for (int i = 0; i < 4; ++i) {
#pragma unroll
    for (int j = 0; j < 4; ++j) {
      int col = n0 + nw + j * 16 + l16;
      if (col < COLS) {
        int b = col / FRAMES;
        int o = col - b * FRAMES;
        int rowb = m0 + mw + i * 16 + quad * 4;
        float* op = out + (size_t)b * N_ * FRAMES + (size_t)rowb * FRAMES + o;
#pragma unroll
        for (int r = 0; r < 4; ++r) op[(size_t)r * FRAMES] = acc[i][j][r];
      }
    }
  }
}

// ---------------- Fallback: direct fp32 conv (if ws too small) --------------
__global__ void naive_conv(const float* __restrict__ x, const float* __restrict__ f,
                           float* __restrict__ out) {
  int col = blockIdx.x;
  int k = threadIdx.x;
  __shared__ float win[1024];
  int b = col / FRAMES;
  int o = col - b * FRAMES;
  const float* xb = x + (size_t)b * LEN;
  int g = o * N_ - N_;
  for (int t = threadIdx.x; t < 1024; t += 512) {
    int i = g + t;
    win[t] = (i >= 0 && i < LEN) ? xb[i] : 0.0f;
  }
  __syncthreads();
  float s = 0.0f;
  const float* fk = f + (size_t)k * 1024;
  for (int t = 0; t < 1024; ++t) s += win[t] * fk[t];
  out[(size_t)b * N_ * FRAMES + (size_t)k * FRAMES + o] = s;
}

extern "C" void kernel_launch(void* const* d_in, const int* in_sizes, int n_in,
                              void* d_out, int out_size, void* d_ws, size_t ws_size,
                              hipStream_t stream) {
  const float* x = (const float*)d_in[0];
  const float* f = (const float*)d_in[1];
  float* out = (float*)d_out;

  const size_t need = (size_t)512 * 512 * sizeof(_Float16);
  if (ws_size < need) {
    naive_conv<<<COLS, 512, 0, stream>>>(x, f, out);
    return;
  }

  _Float16* D = (_Float16*)d_ws;
  prep_filter<<<256, 256, 0, stream>>>(f, D);
  // Grid 1056 = 132*8: s=(nt>>3)*4+m up to 131 for nt=256,m=3 (id 1048).
  // nt>=257 tail blocks exit immediately.
  gemm_fused<<<1056, 256, 0, stream>>>(D, x, out);
}